// Round 3
// baseline (1543.922 us; speedup 1.0000x reference)
//
#include <hip/hip_runtime.h>
#include <cstddef>

#define NEG_V (-1000000000.0f)
#define INV_SQE 0.04419417382415922f  // 1/sqrt(512)

typedef float4 f4;

// XOR-swizzled LDS addressing: row-major, strideSlots float4-slots per row,
// physical slot = slot ^ (row & m). Keeps ds_read_b128 conflict-free for the
// access patterns below (rows strided so row&m is distinct across lanes).
__device__ __forceinline__ int swz(int row, int col, int strideSlots, int m) {
  int slot = col >> 2;
  return row * (strideSlots << 2) + ((slot ^ (row & m)) << 2) + (col & 3);
}

// ---------------------------------------------------------------------------
// K1: per-head QKV projection. q[b,h,t,o] = sum_s x[b,t,h,s] * Wq[o,s]
// Layout out: (B,H,T,64). block = (b, h, 64-token tile), 256 thr.
// W row per lane in regs; x rows via L1 broadcast loads.
// ---------------------------------------------------------------------------
__global__ __launch_bounds__(256) void k_qkv(
    const float* __restrict__ x, const float* __restrict__ Wq,
    const float* __restrict__ Wk, const float* __restrict__ Wv,
    float* __restrict__ qo, float* __restrict__ ko, float* __restrict__ vo) {
  int bid = blockIdx.x;
  int b = bid >> 7, h = (bid >> 4) & 7, tt = bid & 15;
  int t0 = tt * 64 + (threadIdx.x >> 6) * 16;
  int o = threadIdx.x & 63;
  const float* Ws[3] = {Wq, Wk, Wv};
  float* outs[3] = {qo, ko, vo};
  size_t obase = (size_t)(b * 8 + h) * 1024 * 64;
  for (int mi = 0; mi < 3; ++mi) {
    f4 w[16];
    const f4* wr = (const f4*)(Ws[mi] + o * 64);
#pragma unroll
    for (int s4 = 0; s4 < 16; ++s4) w[s4] = wr[s4];
    float* op = outs[mi] + obase;
#pragma unroll 4
    for (int j = 0; j < 16; ++j) {
      int t = t0 + j;
      const f4* xr = (const f4*)(x + (size_t)(b * 1024 + t) * 512 + h * 64);
      float a = 0.f;
#pragma unroll
      for (int s4 = 0; s4 < 16; ++s4) {
        f4 xv = xr[s4];
        a += w[s4].x * xv.x + w[s4].y * xv.y + w[s4].z * xv.z + w[s4].w * xv.w;
      }
      op[(size_t)t * 64 + o] = a;
    }
  }
}

// ---------------------------------------------------------------------------
// K1b: vmean[b,h,s] = mean_t v[b,h,t,s]  (exact output for masked query rows:
// reference masks the QUERY axis -> whole score row == NEG -> uniform softmax
// over all 1024 keys -> output = mean_t v)
// ---------------------------------------------------------------------------
__global__ __launch_bounds__(256) void k_vmean(const float* __restrict__ v,
                                               float* __restrict__ vmean) {
  int bh = blockIdx.x;
  int s = threadIdx.x & 63, tg = threadIdx.x >> 6;
  __shared__ float red[256];
  const float* vp = v + ((size_t)bh * 1024 + tg * 256) * 64 + s;
  float sum = 0.f;
  for (int t = 0; t < 256; ++t) sum += vp[(size_t)t * 64];
  red[threadIdx.x] = sum;
  __syncthreads();
  if (tg == 0)
    vmean[bh * 64 + s] =
        (red[s] + red[64 + s] + red[128 + s] + red[192 + s]) * (1.0f / 1024.0f);
}

// ---------------------------------------------------------------------------
// K2: fused flash attention with relative position term.
// block = (b, h, 64-query tile), 256 thr, 131.5 KB LDS (1 block/CU; gfx950
// allows up to 160 KB/workgroup — AITER attn uses 160 KB).
// Per key tile: fused GEMM [S1|D] = Q @ [K | ErBand]^T, online softmax, PV.
// scores[i][j] = S1[i][j]/sqrt(512) + D[i][63 + j - i]   (j<=i causal)
// where ErBand row dd = Er[h][mbase+dd], mbase = 960 + 64*(kt-qt).
// ---------------------------------------------------------------------------
__global__ __launch_bounds__(256) void k_attn(
    const float* __restrict__ qg_, const float* __restrict__ kg_,
    const float* __restrict__ vg_, const float* __restrict__ Er,
    const int* __restrict__ mask, const float* __restrict__ vmean,
    float* __restrict__ att) {
  __shared__ float lds[32896];   // 131584 B
  float* lq = lds;               // Q    : 64 rows x 16 slots
  float* lb = lds + 4096;        // K|Er : 192 rows x 16 slots
  float* lv = lds + 16384;       // V    : 64 rows x 16 slots
  float* sd = lds + 20480;       // S1|D : 64 rows x 48 slots (S1 -> P in place)
  float* st = lds + 32768;       // per-row {rescale, l}

  const int tid = threadIdx.x;
  const int bid = blockIdx.x;
  const int qt = bid & 15, h = (bid >> 4) & 7, b = bid >> 7;
  const int i0 = qt * 64;
  const int bh = b * 8 + h;

  // stage Q once
  const float* qsrc = qg_ + ((size_t)bh * 1024 + i0) * 64;
#pragma unroll
  for (int e = 0; e < 4; ++e) {
    int fid = tid + e * 256;
    int row = fid >> 4, slot = fid & 15;
    *(f4*)(lq + swz(row, slot * 4, 16, 15)) =
        *(const f4*)(qsrc + row * 64 + slot * 4);
  }

  // softmax-phase mapping: 4 lanes per query row
  const int ci = tid >> 2, cgl = tid & 3;
  float m_run = -3.0e38f, l_run = 0.f;
  // PV / GEMM mapping: 16x16 thread grid
  const int rg = tid >> 4, cgm = tid & 15;
  f4 acc[4];
#pragma unroll
  for (int r = 0; r < 4; ++r) acc[r] = f4{0.f, 0.f, 0.f, 0.f};

  const float* kg = kg_ + (size_t)bh * 1024 * 64;
  const float* vg = vg_ + (size_t)bh * 1024 * 64;
  const float* eg = Er + (size_t)h * 1024 * 64;

  for (int kt = 0; kt <= qt; ++kt) {
    // ---- stage K, V, Er band ----
    {
      const float* ks = kg + kt * 64 * 64;
      const float* vs = vg + kt * 64 * 64;
#pragma unroll
      for (int e = 0; e < 4; ++e) {
        int fid = tid + e * 256;
        int row = fid >> 4, slot = fid & 15;
        *(f4*)(lb + swz(row, slot * 4, 16, 15)) =
            *(const f4*)(ks + row * 64 + slot * 4);
        *(f4*)(lv + swz(row, slot * 4, 16, 15)) =
            *(const f4*)(vs + row * 64 + slot * 4);
      }
      int mbase = 960 + (kt - qt) * 64;
#pragma unroll
      for (int e = 0; e < 8; ++e) {
        int fid = tid + e * 256;
        int row = fid >> 4, slot = fid & 15;
        int mm = mbase + row;
        f4 val = {0.f, 0.f, 0.f, 0.f};
        if (mm <= 1023) val = *(const f4*)(eg + (size_t)mm * 64 + slot * 4);
        *(f4*)(lb + swz(64 + row, slot * 4, 16, 15)) = val;
      }
    }
    __syncthreads();

    // ---- fused GEMM: sd[64][192] = Q @ [K|Er]^T; micro 4 rows x 12 cols ----
    {
      float am[4][12];
#pragma unroll
      for (int r = 0; r < 4; ++r)
#pragma unroll
        for (int u = 0; u < 12; ++u) am[r][u] = 0.f;
#pragma unroll
      for (int s4 = 0; s4 < 16; ++s4) {
        f4 qv[4];
#pragma unroll
        for (int r = 0; r < 4; ++r)
          qv[r] = *(const f4*)(lq + swz(rg * 4 + r, s4 * 4, 16, 15));
#pragma unroll
        for (int u = 0; u < 12; ++u) {
          f4 bv = *(const f4*)(lb + swz(cgm + u * 16, s4 * 4, 16, 15));
#pragma unroll
          for (int r = 0; r < 4; ++r)
            am[r][u] += qv[r].x * bv.x + qv[r].y * bv.y + qv[r].z * bv.z +
                        qv[r].w * bv.w;
        }
      }
#pragma unroll
      for (int r = 0; r < 4; ++r)
#pragma unroll
        for (int u = 0; u < 12; ++u)
          sd[swz(rg * 4 + r, cgm + u * 16, 48, 15)] = am[r][u];
    }
    __syncthreads();

    // ---- online softmax (4 lanes/row, shfl_xor reduce) ----
    {
      const int gi = i0 + ci;
      float sv[16];
      float mloc = -3.0e38f;
#pragma unroll
      for (int c = 0; c < 16; ++c) {
        int j = c * 4 + cgl;
        int gj = kt * 64 + j;
        float valv = NEG_V;
        if (gj <= gi) {
          float s1 = sd[swz(ci, j, 48, 15)];
          float dr = sd[swz(ci, 127 + j - ci, 48, 15)];
          valv = s1 * INV_SQE + dr;
        }
        sv[c] = valv;
        mloc = fmaxf(mloc, valv);
      }
      mloc = fmaxf(mloc, __shfl_xor(mloc, 1));
      mloc = fmaxf(mloc, __shfl_xor(mloc, 2));
      float m_new = fmaxf(m_run, mloc);
      float fs = __expf(m_run - m_new);
      float lsum = 0.f;
#pragma unroll
      for (int c = 0; c < 16; ++c) {
        float p = __expf(sv[c] - m_new);
        sv[c] = p;
        lsum += p;
      }
      lsum += __shfl_xor(lsum, 1);
      lsum += __shfl_xor(lsum, 2);
      l_run = l_run * fs + lsum;
      m_run = m_new;
#pragma unroll
      for (int c = 0; c < 16; ++c)
        sd[swz(ci, c * 4 + cgl, 48, 15)] = sv[c];  // P in place of S1
      if (cgl == 0) {
        st[ci * 2] = fs;
        st[ci * 2 + 1] = l_run;
      }
    }
    __syncthreads();

    // ---- PV: acc(4x4 micro) += P @ V ----
    {
#pragma unroll
      for (int r = 0; r < 4; ++r) {
        float fs = st[(rg * 4 + r) * 2];
        acc[r].x *= fs; acc[r].y *= fs; acc[r].z *= fs; acc[r].w *= fs;
      }
#pragma unroll
      for (int j4 = 0; j4 < 16; ++j4) {
        f4 pv[4], vv[4];
#pragma unroll
        for (int r = 0; r < 4; ++r)
          pv[r] = *(const f4*)(sd + swz(rg * 4 + r, j4 * 4, 48, 15));
#pragma unroll
        for (int u = 0; u < 4; ++u)
          vv[u] = *(const f4*)(lv + swz(j4 * 4 + u, cgm * 4, 16, 15));
#pragma unroll
        for (int r = 0; r < 4; ++r) {
          acc[r].x += pv[r].x * vv[0].x + pv[r].y * vv[1].x + pv[r].z * vv[2].x + pv[r].w * vv[3].x;
          acc[r].y += pv[r].x * vv[0].y + pv[r].y * vv[1].y + pv[r].z * vv[2].y + pv[r].w * vv[3].y;
          acc[r].z += pv[r].x * vv[0].z + pv[r].y * vv[1].z + pv[r].z * vv[2].z + pv[r].w * vv[3].z;
          acc[r].w += pv[r].x * vv[0].w + pv[r].y * vv[1].w + pv[r].z * vv[2].w + pv[r].w * vv[3].w;
        }
      }
    }
    __syncthreads();
  }

  // ---- epilogue: divide by l; masked query rows -> mean(V); store (B,T,512)
  {
    f4 vmv = *(const f4*)(vmean + bh * 64 + cgm * 4);
#pragma unroll
    for (int r = 0; r < 4; ++r) {
      int row = rg * 4 + r;
      int t = i0 + row;
      float invl = 1.0f / st[row * 2 + 1];
      f4 o;
      if (mask[b * 1024 + t] == 0) {
        o = vmv;
      } else {
        o.x = acc[r].x * invl; o.y = acc[r].y * invl;
        o.z = acc[r].z * invl; o.w = acc[r].w * invl;
      }
      *(f4*)(att + (size_t)(b * 1024 + t) * 512 + h * 64 + cgm * 4) = o;
    }
  }
}

// ---------------------------------------------------------------------------
// K3: out = att(8192x512) @ Wo^T + bo. 64x64 tiles, K-tile 32, 4x4 micro
// (strided rows/cols so swizzle keeps ds_read_b128 conflict-free).
// ---------------------------------------------------------------------------
__global__ __launch_bounds__(256) void k_oproj(
    const float* __restrict__ A, const float* __restrict__ Wo,
    const float* __restrict__ bo, float* __restrict__ out) {
  __shared__ float la[2048];
  __shared__ float lw[2048];
  const int tid = threadIdx.x;
  const int bid = blockIdx.x;
  const int rb = bid >> 3, cb = bid & 7;
  const int r0 = rb * 64, c0 = cb * 64;
  const int rg = tid >> 4, cg = tid & 15;
  float am[4][4];
#pragma unroll
  for (int r = 0; r < 4; ++r)
#pragma unroll
    for (int c = 0; c < 4; ++c) am[r][c] = 0.f;

  for (int kt = 0; kt < 16; ++kt) {
#pragma unroll
    for (int e = 0; e < 2; ++e) {
      int fid = tid * 2 + e;
      int row = fid >> 3, slot = fid & 7;
      *(f4*)(la + swz(row, slot * 4, 8, 7)) =
          *(const f4*)(A + (size_t)(r0 + row) * 512 + kt * 32 + slot * 4);
      *(f4*)(lw + swz(row, slot * 4, 8, 7)) =
          *(const f4*)(Wo + (size_t)(c0 + row) * 512 + kt * 32 + slot * 4);
    }
    __syncthreads();
#pragma unroll
    for (int k4 = 0; k4 < 8; ++k4) {
      f4 av[4], wv[4];
#pragma unroll
      for (int r = 0; r < 4; ++r)
        av[r] = *(const f4*)(la + swz(rg + r * 16, k4 * 4, 8, 7));
#pragma unroll
      for (int c = 0; c < 4; ++c)
        wv[c] = *(const f4*)(lw + swz(cg + c * 16, k4 * 4, 8, 7));
#pragma unroll
      for (int r = 0; r < 4; ++r)
#pragma unroll
        for (int c = 0; c < 4; ++c)
          am[r][c] += av[r].x * wv[c].x + av[r].y * wv[c].y +
                      av[r].z * wv[c].z + av[r].w * wv[c].w;
    }
    __syncthreads();
  }
#pragma unroll
  for (int r = 0; r < 4; ++r)
#pragma unroll
    for (int c = 0; c < 4; ++c) {
      int col = c0 + cg + c * 16;
      out[(size_t)(r0 + rg + r * 16) * 512 + col] = am[r][c] + bo[col];
    }
}

// ---------------------------------------------------------------------------
extern "C" void kernel_launch(void* const* d_in, const int* in_sizes, int n_in,
                              void* d_out, int out_size, void* d_ws,
                              size_t ws_size, hipStream_t stream) {
  (void)in_sizes; (void)n_in; (void)out_size; (void)ws_size;
  const float* x  = (const float*)d_in[0];
  const int*   mk = (const int*)d_in[1];
  const float* Wq = (const float*)d_in[2];
  const float* Wk = (const float*)d_in[3];
  const float* Wv = (const float*)d_in[4];
  const float* Er = (const float*)d_in[5];
  const float* Wo = (const float*)d_in[6];
  const float* bo = (const float*)d_in[7];
  float* out = (float*)d_out;
  float* ws = (float*)d_ws;
  // ws layout (floats): q | k | v | att | vmean   (4M each, +4K) ~= 64 MB
  float* q     = ws;
  float* k     = ws + (size_t)1 * (1u << 22);
  float* v     = ws + (size_t)2 * (1u << 22);
  float* att   = ws + (size_t)3 * (1u << 22);
  float* vmean = ws + (size_t)4 * (1u << 22);

  k_qkv  <<<1024, 256, 0, stream>>>(x, Wq, Wk, Wv, q, k, v);
  k_vmean<<<  64, 256, 0, stream>>>(v, vmean);
  k_attn <<<1024, 256, 0, stream>>>(q, k, v, Er, mk, vmean, att);
  k_oproj<<<1024, 256, 0, stream>>>(att, Wo, bo, out);
}

// Round 9
// 1083.920 us; speedup vs baseline: 1.4244x; 1.4244x over previous
//
#include <hip/hip_runtime.h>
#include <cstddef>
#include <cstdint>

#define NEG_V (-1000000000.0f)
#define INV_SQE 0.04419417382415922f  // 1/sqrt(512)

typedef float f32x4_t __attribute__((ext_vector_type(4)));
typedef short bf16x8_t __attribute__((ext_vector_type(8)));  // 8 bf16 raw bits (guide-verified frag type)

__device__ __forceinline__ unsigned short f2bf(float x) {  // RNE f32->bf16
  union { float f; unsigned u; } v; v.f = x;
  unsigned r = v.u + 0x7fffu + ((v.u >> 16) & 1u);
  return (unsigned short)(r >> 16);
}
__device__ __forceinline__ float bf2f(unsigned short h) {
  union { float f; unsigned u; } v; v.u = ((unsigned)h) << 16;
  return v.f;
}
__device__ __forceinline__ bf16x8_t ldb8(const unsigned short* p) {
  return *(const bf16x8_t*)p;
}
// Compile-time ordering fence for wave-synchronous LDS phases (no runtime op).
// DS ops execute in issue order per wave, so HW visibility is guaranteed; this
// only stops the compiler from hoisting cross-lane ds_reads above ds_writes.
#define WAVE_FENCE() __builtin_amdgcn_wave_barrier()
#define MFMA16(a, b, c) __builtin_amdgcn_mfma_f32_16x16x32_bf16((a), (b), (c), 0, 0, 0)

// ---------------------------------------------------------------------------
// k_cvt: generic f32 -> (hi,lo) split-bf16. x ~= hi + lo, |err| ~ 2^-17 |x|.
// ---------------------------------------------------------------------------
__global__ __launch_bounds__(256) void k_cvt(const float* __restrict__ src,
                                             unsigned short* __restrict__ hi,
                                             unsigned short* __restrict__ lo,
                                             int n) {
  int i = blockIdx.x * 256 + threadIdx.x;
  if (i < n) {
    float x = src[i];
    unsigned short h = f2bf(x);
    hi[i] = h;
    lo[i] = f2bf(x - bf2f(h));
  }
}

// ---------------------------------------------------------------------------
// k_qkv: per-head QKV projection with split-bf16 outputs.
// q,k: [bh][1024][64] hi/lo (A / B^T row-major, k-contiguous fragments).
// v  : emitted TRANSPOSED vT [bh][64 dim][1024 key] hi/lo (B-fragment layout
//      for PV) via an LDS transpose so global writes stay coalesced.
// ---------------------------------------------------------------------------
__global__ __launch_bounds__(256) void k_qkv(
    const float* __restrict__ x, const float* __restrict__ Wq,
    const float* __restrict__ Wk, const float* __restrict__ Wv,
    unsigned short* __restrict__ qhi, unsigned short* __restrict__ qlo,
    unsigned short* __restrict__ khi, unsigned short* __restrict__ klo,
    unsigned short* __restrict__ vthi, unsigned short* __restrict__ vtlo) {
  __shared__ float vtile[64 * 65];  // +1 pad: conflict-free column reads
  int bid = blockIdx.x;
  int b = bid >> 7, h = (bid >> 4) & 7, tt = bid & 15;
  int tg = threadIdx.x >> 6, o = threadIdx.x & 63;
  int t0 = tt * 64 + tg * 16;
  size_t bh = (size_t)(b * 8 + h);

  const float4* wq = (const float4*)(Wq + o * 64);
  const float4* wk = (const float4*)(Wk + o * 64);
  const float4* wv = (const float4*)(Wv + o * 64);
  float4 rq[16], rk[16], rv[16];
#pragma unroll
  for (int s4 = 0; s4 < 16; ++s4) { rq[s4] = wq[s4]; rk[s4] = wk[s4]; rv[s4] = wv[s4]; }

#pragma unroll 2
  for (int j = 0; j < 16; ++j) {
    int t = t0 + j;
    const float4* xr = (const float4*)(x + (size_t)(b * 1024 + t) * 512 + h * 64);
    float aq = 0.f, ak = 0.f, av = 0.f;
#pragma unroll
    for (int s4 = 0; s4 < 16; ++s4) {
      float4 xv = xr[s4];
      aq += rq[s4].x * xv.x + rq[s4].y * xv.y + rq[s4].z * xv.z + rq[s4].w * xv.w;
      ak += rk[s4].x * xv.x + rk[s4].y * xv.y + rk[s4].z * xv.z + rk[s4].w * xv.w;
      av += rv[s4].x * xv.x + rv[s4].y * xv.y + rv[s4].z * xv.z + rv[s4].w * xv.w;
    }
    size_t qi = (bh * 1024 + t) * 64 + o;
    unsigned short hq = f2bf(aq), hk = f2bf(ak);
    qhi[qi] = hq; qlo[qi] = f2bf(aq - bf2f(hq));
    khi[qi] = hk; klo[qi] = f2bf(ak - bf2f(hk));
    vtile[(tg * 16 + j) * 65 + o] = av;
  }
  __syncthreads();
  // transpose-out v: thread (dg=tid>>6, tl=tid&63) writes vT[d][t0+tl] coalesced
  int dg = tg, tl = o;
#pragma unroll
  for (int i = 0; i < 16; ++i) {
    int d = dg * 16 + i;
    float val = vtile[tl * 65 + d];
    unsigned short hv = f2bf(val);
    size_t vi = (bh * 64 + d) * 1024 + tt * 64 + tl;
    vthi[vi] = hv;
    vtlo[vi] = f2bf(val - bf2f(hv));
  }
}

// ---------------------------------------------------------------------------
// k_vmean: vmean[bh][d] = mean_t v (from vT hi+lo). Masked-query-row output.
// ---------------------------------------------------------------------------
__global__ __launch_bounds__(256) void k_vmean(const unsigned short* __restrict__ vthi,
                                               const unsigned short* __restrict__ vtlo,
                                               float* __restrict__ vmean) {
  int bh = blockIdx.x;
  int d = threadIdx.x >> 2, part = threadIdx.x & 3;
  size_t base = ((size_t)bh * 64 + d) * 1024 + part * 256;
  float sum = 0.f;
#pragma unroll 4
  for (int i = 0; i < 32; ++i) {
    bf16x8_t a = ldb8(vthi + base + i * 8);
    bf16x8_t b = ldb8(vtlo + base + i * 8);
#pragma unroll
    for (int e = 0; e < 8; ++e)
      sum += bf2f((unsigned short)a[e]) + bf2f((unsigned short)b[e]);
  }
  sum += __shfl_xor(sum, 1);
  sum += __shfl_xor(sum, 2);
  if (part == 0) vmean[bh * 64 + d] = sum * (1.0f / 1024.0f);
}

// ---------------------------------------------------------------------------
// k_attn: MFMA flash attention w/ relative term. 256 thr = 4 waves, each wave
// owns a 16-query-row strip: fused [S1|D] = Q @ [K|ErBand]^T, online softmax,
// PV — all strip-local => ZERO __syncthreads in the kt loop (wave-synchronous
// LDS with WAVE_FENCE compile-time ordering).
// B-fragments (K, Er, vT) read directly from global (L2-resident).
// Output: f32 att directly into d_out (B,T,512). LDS 68,096 B => 2 blocks/CU.
// ---------------------------------------------------------------------------
__global__ __launch_bounds__(256) void k_attn(
    const unsigned short* __restrict__ qhi, const unsigned short* __restrict__ qlo,
    const unsigned short* __restrict__ khi, const unsigned short* __restrict__ klo,
    const unsigned short* __restrict__ vthi, const unsigned short* __restrict__ vtlo,
    const unsigned short* __restrict__ erhi, const unsigned short* __restrict__ erlo,
    const int* __restrict__ mask, const float* __restrict__ vmean,
    float* __restrict__ attf) {
  __shared__ float s1[64 * 68];            // scores S1, stride 68 (bank-spread)
  __shared__ float dld[64 * 132];          // D (QEr band), stride 132
  __shared__ unsigned short plds_h[64 * 64];  // P hi, 16B-slot XOR swizzle
  __shared__ unsigned short plds_l[64 * 64];  // P lo
  __shared__ float st_fs[64];              // per-row rescale factor
  __shared__ float st_l[64];               // per-row final l

  const int tid = threadIdx.x;
  const int bid = blockIdx.x;
  const int qt = 15 - (bid & 15);          // heavy blocks first (tail balance)
  const int h = (bid >> 4) & 7, b = bid >> 7;
  const int i0 = qt * 64;
  const size_t bh = (size_t)(b * 8 + h);

  const int wave = tid >> 6, l = tid & 63;
  const int lr = l & 15, lg = l >> 4;      // fragment row / k-group
  const int ci = tid >> 2, cgl = tid & 3;  // softmax: row (own wave's strip), col group

  // Q fragments in registers (A operand: row = lr, k-contiguous 8)
  const size_t qrow = (bh * 1024 + i0 + wave * 16 + lr) * 64;
  bf16x8_t qh0 = ldb8(qhi + qrow + lg * 8);
  bf16x8_t qh1 = ldb8(qhi + qrow + 32 + lg * 8);
  bf16x8_t ql0 = ldb8(qlo + qrow + lg * 8);
  bf16x8_t ql1 = ldb8(qlo + qrow + 32 + lg * 8);

  f32x4_t oacc[4];
#pragma unroll
  for (int ct = 0; ct < 4; ++ct) oacc[ct] = (f32x4_t){0.f, 0.f, 0.f, 0.f};
  float m_run = -3.0e38f, l_run = 0.f;

  for (int kt = 0; kt <= qt; ++kt) {
    const int mbase = 960 + (kt - qt) * 64;

    // ---- S1 = Q @ K^T (4 column tiles) ----
#pragma unroll
    for (int ct = 0; ct < 4; ++ct) {
      if (kt == qt && ct * 16 > wave * 16 + 15) continue;  // fully causal-masked
      const size_t krow = (bh * 1024 + kt * 64 + ct * 16 + lr) * 64;
      bf16x8_t kh0 = ldb8(khi + krow + lg * 8);
      bf16x8_t kh1 = ldb8(khi + krow + 32 + lg * 8);
      bf16x8_t kl0 = ldb8(klo + krow + lg * 8);
      bf16x8_t kl1 = ldb8(klo + krow + 32 + lg * 8);
      f32x4_t acc = (f32x4_t){0.f, 0.f, 0.f, 0.f};
      acc = MFMA16(qh0, kh0, acc); acc = MFMA16(qh1, kh1, acc);
      acc = MFMA16(ql0, kh0, acc); acc = MFMA16(ql1, kh1, acc);
      acc = MFMA16(qh0, kl0, acc); acc = MFMA16(qh1, kl1, acc);
#pragma unroll
      for (int r = 0; r < 4; ++r)
        s1[(wave * 16 + lg * 4 + r) * 68 + ct * 16 + lr] = acc[r];
    }
    // ---- D = Q @ ErBand^T (8 column tiles; band row dd = Er[mbase+dd]) ----
#pragma unroll
    for (int et = 0; et < 8; ++et) {
      const int m0 = mbase + et * 16;
      if (m0 > 1023) continue;  // only on kt==qt; region never read then
      const size_t erow = ((size_t)h * 1024 + m0 + lr) * 64;
      bf16x8_t eh0 = ldb8(erhi + erow + lg * 8);
      bf16x8_t eh1 = ldb8(erhi + erow + 32 + lg * 8);
      bf16x8_t el0 = ldb8(erlo + erow + lg * 8);
      bf16x8_t el1 = ldb8(erlo + erow + 32 + lg * 8);
      f32x4_t acc = (f32x4_t){0.f, 0.f, 0.f, 0.f};
      acc = MFMA16(qh0, eh0, acc); acc = MFMA16(qh1, eh1, acc);
      acc = MFMA16(ql0, eh0, acc); acc = MFMA16(ql1, eh1, acc);
      acc = MFMA16(qh0, el0, acc); acc = MFMA16(qh1, el1, acc);
#pragma unroll
      for (int r = 0; r < 4; ++r)
        dld[(wave * 16 + lg * 4 + r) * 132 + et * 16 + lr] = acc[r];
    }
    WAVE_FENCE();  // tile stores visible before softmax cross-lane reads

    // ---- online softmax: lane owns (row ci, cols cgl*16..+15) ----
    {
      const int gi = i0 + ci;
      const int j0 = cgl * 16;
      float sv[16];
      const float* s1p = s1 + ci * 68 + j0;
      const int dd0 = 63 + j0 - ci;          // in [0,126] for unmasked cols
      const float* dp = dld + ci * 132 + dd0;
      float mloc = -3.0e38f;
#pragma unroll
      for (int c4 = 0; c4 < 4; ++c4) {
        float4 s4v = *(const float4*)(s1p + c4 * 4);
#pragma unroll
        for (int e = 0; e < 4; ++e) {
          int cc = c4 * 4 + e;
          float s1v = (e == 0) ? s4v.x : (e == 1) ? s4v.y : (e == 2) ? s4v.z : s4v.w;
          float val = s1v * INV_SQE + dp[cc];
          bool ok = (kt * 64 + j0 + cc) <= gi;
          sv[cc] = ok ? val : NEG_V;     // select: NaN/garbage from skipped tiles safe
          mloc = fmaxf(mloc, sv[cc]);
        }
      }
      mloc = fmaxf(mloc, __shfl_xor(mloc, 1));
      mloc = fmaxf(mloc, __shfl_xor(mloc, 2));
      float m_new = fmaxf(m_run, mloc);
      float fs = __expf(m_run - m_new);
      float lsum = 0.f;
      unsigned pk_h[8], pk_l[8];
#pragma unroll
      for (int cc = 0; cc < 16; cc += 2) {
        float p0 = __expf(sv[cc] - m_new);
        float p1 = __expf(sv[cc + 1] - m_new);
        lsum += p0 + p1;
        unsigned short h0 = f2bf(p0), h1 = f2bf(p1);
        unsigned short l0 = f2bf(p0 - bf2f(h0)), l1 = f2bf(p1 - bf2f(h1));
        pk_h[cc >> 1] = (unsigned)h0 | ((unsigned)h1 << 16);
        pk_l[cc >> 1] = (unsigned)l0 | ((unsigned)l1 << 16);
      }
      lsum += __shfl_xor(lsum, 1);
      lsum += __shfl_xor(lsum, 2);
      l_run = l_run * fs + lsum;
      m_run = m_new;
      // P store: logical 16B slot s=cgl*2+e holds keys s*8..s*8+7; phys = s^(ci&7)
#pragma unroll
      for (int e = 0; e < 2; ++e) {
        int phys = ((cgl * 2 + e) ^ (ci & 7)) * 8;
        *(uint4*)(plds_h + ci * 64 + phys) =
            make_uint4(pk_h[e * 4], pk_h[e * 4 + 1], pk_h[e * 4 + 2], pk_h[e * 4 + 3]);
        *(uint4*)(plds_l + ci * 64 + phys) =
            make_uint4(pk_l[e * 4], pk_l[e * 4 + 1], pk_l[e * 4 + 2], pk_l[e * 4 + 3]);
      }
      if (cgl == 0) st_fs[ci] = fs;
    }
    WAVE_FENCE();  // P/fs stores visible before PV cross-lane reads

    // ---- PV: oacc = oacc*fs + P @ V (vT B-fragments direct from global) ----
    {
      float fsr[4];
#pragma unroll
      for (int r = 0; r < 4; ++r) fsr[r] = st_fs[wave * 16 + lg * 4 + r];
#pragma unroll
      for (int ct = 0; ct < 4; ++ct) {
#pragma unroll
        for (int r = 0; r < 4; ++r) oacc[ct][r] *= fsr[r];
      }
      const int prow = (wave * 16 + lr) * 64;
      bf16x8_t pa_h0 = ldb8(plds_h + prow + ((lg ^ (lr & 7)) * 8));
      bf16x8_t pa_h1 = ldb8(plds_h + prow + (((4 ^ lg) ^ (lr & 7)) * 8));
      bf16x8_t pa_l0 = ldb8(plds_l + prow + ((lg ^ (lr & 7)) * 8));
      bf16x8_t pa_l1 = ldb8(plds_l + prow + (((4 ^ lg) ^ (lr & 7)) * 8));
#pragma unroll
      for (int ct = 0; ct < 4; ++ct) {
        const size_t vrow = (bh * 64 + ct * 16 + lr) * 1024 + kt * 64;
        bf16x8_t vh0 = ldb8(vthi + vrow + lg * 8);
        bf16x8_t vh1 = ldb8(vthi + vrow + 32 + lg * 8);
        bf16x8_t vl0 = ldb8(vtlo + vrow + lg * 8);
        bf16x8_t vl1 = ldb8(vtlo + vrow + 32 + lg * 8);
        f32x4_t acc = oacc[ct];
        acc = MFMA16(pa_h0, vh0, acc); acc = MFMA16(pa_h1, vh1, acc);
        acc = MFMA16(pa_l0, vh0, acc); acc = MFMA16(pa_l1, vh1, acc);
        acc = MFMA16(pa_h0, vl0, acc); acc = MFMA16(pa_h1, vl1, acc);
        oacc[ct] = acc;
      }
    }
    WAVE_FENCE();  // PV reads complete (in order) before next-iter P stores
  }

  // ---- epilogue: /l, masked-query override with vmean, f32 store to d_out --
  if (cgl == 0) st_l[ci] = l_run;
  WAVE_FENCE();
  float invl[4]; int mk[4];
#pragma unroll
  for (int r = 0; r < 4; ++r) {
    int rr = wave * 16 + lg * 4 + r;
    invl[r] = 1.0f / st_l[rr];
    mk[r] = mask[b * 1024 + i0 + rr];
  }
#pragma unroll
  for (int ct = 0; ct < 4; ++ct) {
    int col = ct * 16 + lr;
    float vm = vmean[bh * 64 + col];
#pragma unroll
    for (int r = 0; r < 4; ++r) {
      int t = i0 + wave * 16 + lg * 4 + r;
      float val = (mk[r] == 0) ? vm : oacc[ct][r] * invl[r];
      attf[(size_t)(b * 1024 + t) * 512 + h * 64 + col] = val;
    }
  }
}

// ---------------------------------------------------------------------------
// k_oproj: IN-PLACE on d_out: io holds f32 att on entry, final out on exit.
// 256 blocks x 32-row strips; block read-set == write-set == own rows, so no
// cross-block hazard. Waves: w&1 -> row half (16 rows), w>>1 -> col half
// (256 cols). Phase 1: stage A-fragments f32->hi/lo regs. __syncthreads.
// Phase 2: MFMA vs pre-split Wo and store (+bias). Split-bf16 3-pass.
// ---------------------------------------------------------------------------
__global__ __launch_bounds__(256) void k_oproj(
    const unsigned short* __restrict__ wohi, const unsigned short* __restrict__ wolo,
    const float* __restrict__ bo, float* io) {
  const int bid = blockIdx.x;
  const int r0 = bid * 32;
  const int wave = threadIdx.x >> 6, l = threadIdx.x & 63;
  const int lr = l & 15, lg = l >> 4;
  const int row = r0 + (wave & 1) * 16 + lr;      // A-fragment row
  const int cbase = (wave >> 1) * 256;            // this wave's col range

  // Phase 1: stage A (att) fragments: 16 K-tiles, lane covers k=ks*32+lg*8..+7
  bf16x8_t ah[16], al[16];
#pragma unroll
  for (int ks = 0; ks < 16; ++ks) {
    const float* ap = io + (size_t)row * 512 + ks * 32 + lg * 8;
    float4 a0 = *(const float4*)(ap);
    float4 a1 = *(const float4*)(ap + 4);
    float f[8] = {a0.x, a0.y, a0.z, a0.w, a1.x, a1.y, a1.z, a1.w};
    bf16x8_t hv, lv;
#pragma unroll
    for (int e = 0; e < 8; ++e) {
      unsigned short hb = f2bf(f[e]);
      hv[e] = (short)hb;
      lv[e] = (short)f2bf(f[e] - bf2f(hb));
    }
    ah[ks] = hv; al[ks] = lv;
  }
  __syncthreads();  // all att reads (whole block) complete before any store

  // Phase 2: out[rows][cbase..+255] = A @ Wo^T + bo
  for (int ct = 0; ct < 16; ++ct) {
    const int col = cbase + ct * 16 + lr;  // B col = Wo row = out col
    f32x4_t acc = (f32x4_t){0.f, 0.f, 0.f, 0.f};
#pragma unroll
    for (int ks = 0; ks < 16; ++ks) {
      const size_t wrow = (size_t)col * 512 + ks * 32 + lg * 8;
      bf16x8_t wh = ldb8(wohi + wrow);
      bf16x8_t wl = ldb8(wolo + wrow);
      acc = MFMA16(ah[ks], wh, acc);
      acc = MFMA16(al[ks], wh, acc);
      acc = MFMA16(ah[ks], wl, acc);
    }
    float bov = bo[col];
#pragma unroll
    for (int r = 0; r < 4; ++r) {
      int orow = r0 + (wave & 1) * 16 + lg * 4 + r;  // C/D row mapping
      io[(size_t)orow * 512 + col] = acc[r] + bov;
    }
  }
}

// ---------------------------------------------------------------------------
extern "C" void kernel_launch(void* const* d_in, const int* in_sizes, int n_in,
                              void* d_out, int out_size, void* d_ws,
                              size_t ws_size, hipStream_t stream) {
  (void)in_sizes; (void)n_in; (void)out_size; (void)ws_size;
  const float* x  = (const float*)d_in[0];
  const int*   mk = (const int*)d_in[1];
  const float* Wq = (const float*)d_in[2];
  const float* Wk = (const float*)d_in[3];
  const float* Wv = (const float*)d_in[4];
  const float* Er = (const float*)d_in[5];
  const float* Wo = (const float*)d_in[6];
  const float* bo = (const float*)d_in[7];
  float* out = (float*)d_out;

  // ws layout: 51.02 MB high-water (proven available >= 67.1 MB from round 3)
  char* wsb = (char*)d_ws;
  const size_t MB = 1u << 20;
  unsigned short* q_hi  = (unsigned short*)(wsb + 0 * MB);
  unsigned short* q_lo  = (unsigned short*)(wsb + 8 * MB);
  unsigned short* k_hi  = (unsigned short*)(wsb + 16 * MB);
  unsigned short* k_lo  = (unsigned short*)(wsb + 24 * MB);
  unsigned short* vT_hi = (unsigned short*)(wsb + 32 * MB);
  unsigned short* vT_lo = (unsigned short*)(wsb + 40 * MB);
  unsigned short* er_hi = (unsigned short*)(wsb + 48 * MB);
  unsigned short* er_lo = (unsigned short*)(wsb + 49 * MB);
  unsigned short* wo_hi = (unsigned short*)(wsb + 50 * MB);
  unsigned short* wo_lo = (unsigned short*)(wsb + 50 * MB + 524288);
  float*          vmean = (float*)(wsb + 51 * MB);

  k_cvt  <<<2048, 256, 0, stream>>>(Er, er_hi, er_lo, 8 * 1024 * 64);
  k_cvt  <<<1024, 256, 0, stream>>>(Wo, wo_hi, wo_lo, 512 * 512);
  k_qkv  <<<1024, 256, 0, stream>>>(x, Wq, Wk, Wv, q_hi, q_lo, k_hi, k_lo, vT_hi, vT_lo);
  k_vmean<<<  64, 256, 0, stream>>>(vT_hi, vT_lo, vmean);
  k_attn <<<1024, 256, 0, stream>>>(q_hi, q_lo, k_hi, k_lo, vT_hi, vT_lo,
                                    er_hi, er_lo, mk, vmean, out);
  k_oproj<<< 256, 256, 0, stream>>>(wo_hi, wo_lo, bo, out);
}